// Round 6
// baseline (510.445 us; speedup 1.0000x reference)
//
#include <hip/hip_runtime.h>

// TS2Vec hierarchical contrastive loss — bf16 MFMA, per-row online flash-LSE.
//
// Pyramid [16][L][C] bf16 per depth (RAW values — no pre-scaling: a Gram
// matrix scales by the SQUARE of any operand pre-scale, which broke R5).
//
// temp: row loss = LSE_{c!=r}(S[r,c]) - S[r,partner], S = Z Z^T, M=2L rows.
// One fused launch, 1448 blocks (depth0 col-split x4, depth1 x2). Block =
// 2 waves x 64 rows; A (whole K=320) in 160 regs/wave; 32-col B tiles staged
// via global_load_lds (fragment-ordered 1KB blobs, conflict-free ds_read_b128)
// double-buffered. Epilogue: PER-ROW online max+sum in raw domain,
//   mn = fmax(m, fmax(v0,v1)); s = s*exp2((m-mn)*L2E) + exp2((v0-mn)*L2E) + ...
// masks (value -3e38, finite => no -inf-(-inf) NaN) only on wave-uniform slow
// tiles (diag/partner/partial/d>=6). st <= M so no overflow; underflow -> 0.
// (m,st) partials to ws; merge kernel folds chunks and applies ln2.
// LDS exactly 40960 B -> 4 blocks/CU; __launch_bounds__(128,2) caps regs.
//
// inst: 16x16 Gram via 10 MFMA (A-frag==B-frag), full max pass (safe for
// pooled depths where dots ~3900), exp/log base-2 via __builtin_amdgcn_*.
// NOTE: never use __exp2f/__log2f (glibc math.h collision in g++ driver mode).

#define B_DIM 8
#define C_DIM 320
#define T_DIM 2048
#define NDEPTH 12
#define LOG2E 1.44269504088896340736f
#define LN2 0.69314718055994530942f
#define FNEG (-3.0e38f)

typedef __attribute__((ext_vector_type(8))) short bf16x8;
typedef __attribute__((ext_vector_type(4))) float f32x4;

#define AS1 __attribute__((address_space(1)))
#define AS3 __attribute__((address_space(3)))

__device__ inline void gload_lds16(const void* g, void* l) {
  __builtin_amdgcn_global_load_lds((const AS1 unsigned int*)g, (AS3 unsigned int*)l,
                                   16, 0, 0);
}

__device__ inline float fast_exp2(float x) { return __builtin_amdgcn_exp2f(x); }
__device__ inline float fast_log2(float x) { return __builtin_amdgcn_logf(x); }

__device__ inline float bf2f(unsigned short s) {
  unsigned u = ((unsigned)s) << 16;
  return __builtin_bit_cast(float, u);
}
__device__ inline unsigned short f2bf(float f) {
  unsigned u = __builtin_bit_cast(unsigned, f);
  u = (u + 0x7FFFu + ((u >> 16) & 1u)) >> 16;  // round-nearest-even
  return (unsigned short)u;
}

// ---------------- tiny utility kernels ----------------
__global__ void zero_kernel(float* acc) {
  if (threadIdx.x < 2) acc[threadIdx.x] = 0.0f;
}

__global__ void finalize_kernel(const float* __restrict__ acc, float* __restrict__ out) {
  if (threadIdx.x == 0) {
    float inst = acc[0] * (1.0f / 11.0f);
    float temp = acc[1] * (1.0f / 11.0f);
    out[0] = 0.5f * inst + 0.5f * temp;  // ALPHA = 0.5
    out[1] = inst;
    out[2] = temp;
  }
}

// ------- transpose+convert: [B][C][T]f32 -> [16][T][C]bf16 (raw) ----------
__global__ __launch_bounds__(256) void transpose_kernel(const float* __restrict__ z1,
                                                        const float* __restrict__ z2,
                                                        unsigned short* __restrict__ out) {
  __shared__ float tile[32][33];
  const int zi = blockIdx.z >> 3;
  const int b = blockIdx.z & 7;
  const float* in = zi ? z2 : z1;
  const int t0 = blockIdx.x * 32;
  const int c0 = blockIdx.y * 32;
  const int tx = threadIdx.x;
  const int ty = threadIdx.y;
#pragma unroll
  for (int k = 0; k < 4; ++k) {
    int c = c0 + ty + k * 8;
    tile[ty + k * 8][tx] = in[((size_t)b * C_DIM + c) * T_DIM + t0 + tx];
  }
  __syncthreads();
#pragma unroll
  for (int k = 0; k < 4; ++k) {
    int t = t0 + ty + k * 8;
    out[((size_t)(zi * B_DIM + b) * T_DIM + t) * C_DIM + c0 + tx] = f2bf(tile[tx][ty + k * 8]);
  }
}

// ---------------- max-pool: one level ------------------------------------
__global__ __launch_bounds__(256) void pool_kernel(const unsigned short* __restrict__ in,
                                                   unsigned short* __restrict__ out,
                                                   int Lout, int n8) {
  int idx = blockIdx.x * 256 + threadIdx.x;
  if (idx >= n8) return;
  int e = idx * 8;
  int c = e % C_DIM;
  int row = e / C_DIM;
  int bb = row / Lout;
  int l = row % Lout;
  size_t base = ((size_t)(bb * 2 * Lout + 2 * l)) * C_DIM + c;
  bf16x8 a = *(const bf16x8*)(in + base);
  bf16x8 b = *(const bf16x8*)(in + base + C_DIM);
  bf16x8 o;
#pragma unroll
  for (int k = 0; k < 8; ++k) {
    unsigned short ua = (unsigned short)a[k], ub = (unsigned short)b[k];
    o[k] = (short)(bf2f(ua) > bf2f(ub) ? ua : ub);
  }
  *(bf16x8*)(out + (size_t)e) = o;
}

// ---------------- max-pool: two levels in one pass -----------------------
__global__ __launch_bounds__(256) void pool2_kernel(const unsigned short* __restrict__ in,
                                                    unsigned short* __restrict__ out1,
                                                    unsigned short* __restrict__ out2,
                                                    int L2out, int n8) {
  int idx = blockIdx.x * 256 + threadIdx.x;
  if (idx >= n8) return;
  int e = idx * 8;
  int c = e % C_DIM;
  int row = e / C_DIM;
  int bb = row / L2out;
  int l = row % L2out;
  size_t base = ((size_t)(bb * 4 * L2out + 4 * l)) * C_DIM + c;
  bf16x8 a = *(const bf16x8*)(in + base);
  bf16x8 b = *(const bf16x8*)(in + base + C_DIM);
  bf16x8 cc = *(const bf16x8*)(in + base + 2 * C_DIM);
  bf16x8 dd = *(const bf16x8*)(in + base + 3 * C_DIM);
  bf16x8 m01, m23, m03;
#pragma unroll
  for (int k = 0; k < 8; ++k) {
    unsigned short ua = (unsigned short)a[k], ub = (unsigned short)b[k];
    unsigned short uc = (unsigned short)cc[k], ud = (unsigned short)dd[k];
    unsigned short x = bf2f(ua) > bf2f(ub) ? ua : ub;
    unsigned short y = bf2f(uc) > bf2f(ud) ? uc : ud;
    m01[k] = (short)x;
    m23[k] = (short)y;
    m03[k] = (short)(bf2f(x) > bf2f(y) ? x : y);
  }
  size_t o1 = ((size_t)(bb * 2 * L2out + 2 * l)) * C_DIM + c;
  *(bf16x8*)(out1 + o1) = m01;
  *(bf16x8*)(out1 + o1 + C_DIM) = m23;
  *(bf16x8*)(out2 + (size_t)e) = m03;
}

// ---------------- fused temp loss ----------------------------------------
__global__ __launch_bounds__(128, 2) void temp_kernel(const unsigned short* __restrict__ pyr,
                                                      float2* __restrict__ ent,
                                                      float* __restrict__ acc) {
  constexpr int Ls[NDEPTH] = {2048, 1024, 512, 256, 128, 64, 32, 16, 8, 4, 2, 1};
  constexpr int SP[NDEPTH] = {4, 2, 1, 1, 1, 1, 1, 1, 1, 1, 1, 1};
  constexpr int NB[NDEPTH] = {1024, 256, 64, 32, 16, 8, 8, 8, 8, 8, 8, 8};
  constexpr size_t ZOFF[NDEPTH] = {0,        10485760, 15728640, 18350080,
                                   19660800, 20316160, 20643840, 20807680,
                                   20889600, 20930560, 20951040, 20961280};
  constexpr size_t EBASE[NDEPTH] = {0,      131072, 163840, 172032, 176128, 178176,
                                    179200, 179712, 179968, 180096, 180160, 180192};
  constexpr float SCL[NDEPTH] = {
      1.f / (16 * 2048.f), 1.f / (16 * 1024.f), 1.f / (16 * 512.f), 1.f / (16 * 256.f),
      1.f / (16 * 128.f),  1.f / (16 * 64.f),   1.f / (16 * 32.f),  1.f / (16 * 16.f),
      1.f / (16 * 8.f),    1.f / (16 * 4.f),    1.f / (16 * 2.f),   1.f / (16 * 1.f)};

  __shared__ __align__(16) unsigned short Bs[2 * 10240];  // exactly 40960 B

  int bid = blockIdx.x;
  int d = 0;
  while (bid >= NB[d]) { bid -= NB[d]; ++d; }
  const int L = Ls[d], M = 2 * L, sp = SP[d];
  const int csz = M / sp;
  const int ntiles = (csz + 31) >> 5;
  const int b = bid & 7;  // batch fastest -> XCD L2 affinity
  const int t2 = bid >> 3;
  const int chunk = t2 % sp;
  const int rb = t2 / sp;
  const int r0 = rb * 128;
  const int cbase = chunk * csz;
  const float scale = SCL[d];
  const unsigned short* Z = pyr + ZOFF[d];

  const int tid = threadIdx.x;
  const int w = tid >> 6, lane = tid & 63;
  const int lr = lane & 15, lg = lane >> 4;

  auto rowptr = [&](int r) -> const unsigned short* {
    r = (r < M) ? r : (M - 1);
    int idx = (r < L) ? (b * L + r) : ((B_DIM + b) * L + (r - L));
    return Z + (size_t)idx * C_DIM;
  };

  auto stage = [&](int buf, int ct) {
    const int c0 = cbase + ct * 32;
#pragma unroll
    for (int i = 0; i < 5; ++i) {
      int ks = w * 5 + i;
#pragma unroll
      for (int sub = 0; sub < 2; ++sub) {
        const unsigned short* g = rowptr(c0 + sub * 16 + lr) + ks * 32 + lg * 8;
        gload_lds16(g, &Bs[buf * 10240 + (ks * 2 + sub) * 512]);
      }
    }
  };

  // A fragments: this wave's 64 rows, whole K (160 regs, AGPR-eligible)
  const int rwave = r0 + w * 64;
  bf16x8 afrag[4][10];
#pragma unroll
  for (int rs = 0; rs < 4; ++rs) {
    const unsigned short* rp = rowptr(rwave + rs * 16 + lr) + lg * 8;
#pragma unroll
    for (int ks = 0; ks < 10; ++ks) afrag[rs][ks] = *(const bf16x8*)(rp + ks * 32);
  }

  // wave-uniform slow-tile ranges
  const int rlo = rwave, rhi = rwave + 63;
  int plo = 1, phi = 0;  // empty
  if (d <= 5) {          // L>=64: wave rows lie in one half (rwave%64==0, 64|L)
    plo = (rlo < L) ? rlo + L : rlo - L;
    phi = plo + 63;
  }

  // per-lane per-row online state (raw domain)
  float m_[16], s_[16];
  float pacc = 0.f;
#pragma unroll
  for (int i = 0; i < 16; ++i) { m_[i] = FNEG; s_[i] = 0.f; }

  stage(0, 0);
  __syncthreads();

  for (int ct = 0; ct < ntiles; ++ct) {
    const int cur = ct & 1;
    if (ct + 1 < ntiles) stage(1 - cur, ct + 1);

    f32x4 c4[4][2];
#pragma unroll
    for (int rs = 0; rs < 4; ++rs)
#pragma unroll
      for (int cs = 0; cs < 2; ++cs) c4[rs][cs] = (f32x4){0.f, 0.f, 0.f, 0.f};

#pragma unroll
    for (int ks = 0; ks < 10; ++ks) {
      bf16x8 b0 = *(const bf16x8*)&Bs[cur * 10240 + (ks * 2 + 0) * 512 + lane * 8];
      bf16x8 b1 = *(const bf16x8*)&Bs[cur * 10240 + (ks * 2 + 1) * 512 + lane * 8];
#pragma unroll
      for (int rs = 0; rs < 4; ++rs) {
        c4[rs][0] = __builtin_amdgcn_mfma_f32_16x16x32_bf16(afrag[rs][ks], b0, c4[rs][0], 0, 0, 0);
        c4[rs][1] = __builtin_amdgcn_mfma_f32_16x16x32_bf16(afrag[rs][ks], b1, c4[rs][1], 0, 0, 0);
      }
    }

    const int gclo = cbase + ct * 32, gchi = gclo + 31;
    bool slow = (d >= 6) ||
                (gchi >= rlo && gclo <= rhi) ||   // diagonal in tile
                (gchi >= plo && gclo <= phi);     // partner col in tile

    if (slow) {
      const int gc0 = gclo + lr, gc1 = gc0 + 16;
#pragma unroll
      for (int rs = 0; rs < 4; ++rs) {
#pragma unroll
        for (int rg = 0; rg < 4; ++rg) {
          int gr = rwave + rs * 16 + lg * 4 + rg;
          int prt = (gr < L) ? (gr + L) : (gr - L);
          float v0 = c4[rs][0][rg], v1 = c4[rs][1][rg];
          if (gr < M) {
            if (gc0 == prt) pacc += v0;
            if (gc1 == prt) pacc += v1;
          }
          float x0 = (gc0 < M && gc0 != gr) ? v0 : FNEG;
          float x1 = (gc1 < M && gc1 != gr) ? v1 : FNEG;
          int i = rs * 4 + rg;
          float mn = fmaxf(m_[i], fmaxf(x0, x1));
          float f = (m_[i] - mn) * LOG2E;   // may overflow to -inf: exp2->0, no NaN
          s_[i] = s_[i] * fast_exp2(f) + fast_exp2((x0 - mn) * LOG2E) +
                  fast_exp2((x1 - mn) * LOG2E);
          m_[i] = mn;
        }
      }
    } else {  // fast path: no masks, no compares
#pragma unroll
      for (int rs = 0; rs < 4; ++rs) {
#pragma unroll
        for (int rg = 0; rg < 4; ++rg) {
          float v0 = c4[rs][0][rg], v1 = c4[rs][1][rg];
          int i = rs * 4 + rg;
          float mn = fmaxf(m_[i], fmaxf(v0, v1));
          float f = (m_[i] - mn) * LOG2E;
          s_[i] = s_[i] * fast_exp2(f) + fast_exp2((v0 - mn) * LOG2E) +
                  fast_exp2((v1 - mn) * LOG2E);
          m_[i] = mn;
        }
      }
    }
    __syncthreads();
  }

  // merge (m,s) across the 16 lr-lanes of each row, write per-row-chunk partial
#pragma unroll
  for (int rs = 0; rs < 4; ++rs) {
#pragma unroll
    for (int rg = 0; rg < 4; ++rg) {
      int i = rs * 4 + rg;
      float m = m_[i], s = s_[i];
      float mt = m;
#pragma unroll
      for (int k = 1; k < 16; k <<= 1) mt = fmaxf(mt, __shfl_xor(mt, k));
      float st = s * fast_exp2((m - mt) * LOG2E);
#pragma unroll
      for (int k = 1; k < 16; k <<= 1) st += __shfl_xor(st, k);
      int gr = rwave + rs * 16 + lg * 4 + rg;
      if (gr < M && lr == 0)
        ent[EBASE[d] + ((size_t)(b * M + gr)) * sp + chunk] = make_float2(mt, st);
    }
  }

  // positives: raw domain, one atomic per wave
#pragma unroll
  for (int k = 1; k < 64; k <<= 1) pacc += __shfl_xor(pacc, k);
  if (lane == 0) atomicAdd(acc + 1, -pacc * scale);
}

// ---------------- merge column-chunk partials -> temp loss ----------------
__global__ __launch_bounds__(256) void merge_kernel(const float2* __restrict__ ent,
                                                    float* __restrict__ acc) {
  constexpr int Ls[NDEPTH] = {2048, 1024, 512, 256, 128, 64, 32, 16, 8, 4, 2, 1};
  constexpr int SP[NDEPTH] = {4, 2, 1, 1, 1, 1, 1, 1, 1, 1, 1, 1};
  constexpr size_t EBASE[NDEPTH] = {0,      131072, 163840, 172032, 176128, 178176,
                                    179200, 179712, 179968, 180096, 180160, 180192};
  constexpr int RBASE[NDEPTH] = {0,     32768, 49152, 57344, 61440, 63488,
                                 64512, 65024, 65280, 65408, 65472, 65504};
  __shared__ float red[4];
  int i = blockIdx.x * 256 + threadIdx.x;
  float partial = 0.f;
  if (i < 65520) {
    int d = 0;
    while (d < 11 && i >= RBASE[d + 1]) ++d;
    int rem = i - RBASE[d];
    int sp = SP[d];
    const float2* e = ent + EBASE[d] + (size_t)rem * sp;
    float mt = FNEG;
    for (int c = 0; c < sp; ++c) mt = fmaxf(mt, e[c].x);
    float st = 0.f;
    for (int c = 0; c < sp; ++c) st += e[c].y * fast_exp2((e[c].x - mt) * LOG2E);
    // natural-log LSE = mt + ln2 * log2(st)
    partial = (mt + LN2 * fast_log2(st)) / (16.f * (float)Ls[d]);
  }
#pragma unroll
  for (int k = 1; k < 64; k <<= 1) partial += __shfl_xor(partial, k);
  if ((threadIdx.x & 63) == 0) red[threadIdx.x >> 6] = partial;
  __syncthreads();
  if (threadIdx.x == 0) atomicAdd(acc + 1, red[0] + red[1] + red[2] + red[3]);
}

// ---------------- fused inst loss: 16x16 Gram via MFMA --------------------
__global__ __launch_bounds__(256) void inst_kernel(const unsigned short* __restrict__ pyr,
                                                   float* __restrict__ acc) {
  constexpr int Ls[NDEPTH] = {2048, 1024, 512, 256, 128, 64, 32, 16, 8, 4, 2, 1};
  constexpr size_t ZOFF[NDEPTH] = {0,        10485760, 15728640, 18350080,
                                   19660800, 20316160, 20643840, 20807680,
                                   20889600, 20930560, 20951040, 20961280};
  constexpr float SCL[NDEPTH] = {
      1.f / (16 * 2048.f), 1.f / (16 * 1024.f), 1.f / (16 * 512.f), 1.f / (16 * 256.f),
      1.f / (16 * 128.f),  1.f / (16 * 64.f),   1.f / (16 * 32.f),  1.f / (16 * 16.f),
      1.f / (16 * 8.f),    1.f / (16 * 4.f),    1.f / (16 * 2.f),   1.f / (16 * 1.f)};
  __shared__ float red[4];
  const int tid = threadIdx.x;
  const int w = tid >> 6, lane = tid & 63, lr = lane & 15, lg = lane >> 4;
  const int gw = blockIdx.x * 4 + w;
  const int nw = gridDim.x * 4;
  float partial = 0.f;

  for (int gl = gw; gl < 4095; gl += nw) {
    int d = 0, l = gl;
    while (l >= Ls[d]) { l -= Ls[d]; ++d; }
    const int L = Ls[d];
    const unsigned short* Z = pyr + ZOFF[d];

    const unsigned short* rp = Z + ((size_t)lr * L + l) * C_DIM + lg * 8;
    bf16x8 fr[10];
#pragma unroll
    for (int ks = 0; ks < 10; ++ks) fr[ks] = *(const bf16x8*)(rp + ks * 32);
    f32x4 c4 = (f32x4){0.f, 0.f, 0.f, 0.f};
#pragma unroll
    for (int ks = 0; ks < 10; ++ks)
      c4 = __builtin_amdgcn_mfma_f32_16x16x32_bf16(fr[ks], fr[ks], c4, 0, 0, 0);

#pragma unroll
    for (int rg = 0; rg < 4; ++rg) {
      int gr = lg * 4 + rg, gc = lr;
      float v = c4[rg];
      int prt = (gr + 8) & 15;
      float ps = (gc == prt) ? v : 0.f;
      float x = (gc != gr) ? v * LOG2E : FNEG * 1.0f;
      float mx = x;
#pragma unroll
      for (int k = 1; k < 16; k <<= 1) mx = fmaxf(mx, __shfl_xor(mx, k));
      float se = fast_exp2(fmaxf(x - mx, -128.f));
#pragma unroll
      for (int k = 1; k < 16; k <<= 1) {
        se += __shfl_xor(se, k);
        ps += __shfl_xor(ps, k);
      }
      if (lr == 0) partial += ((mx + fast_log2(se)) * LN2 - ps) * SCL[d];
    }
  }

#pragma unroll
  for (int k = 1; k < 64; k <<= 1) partial += __shfl_xor(partial, k);
  if ((tid & 63) == 0) red[tid >> 6] = partial;
  __syncthreads();
  if (tid == 0) atomicAdd(acc, red[0] + red[1] + red[2] + red[3]);
}

// ---------------- launch ----------------
extern "C" void kernel_launch(void* const* d_in, const int* in_sizes, int n_in,
                              void* d_out, int out_size, void* d_ws, size_t ws_size,
                              hipStream_t stream) {
  const float* z1 = (const float*)d_in[0];
  const float* z2 = (const float*)d_in[1];
  float* out = (float*)d_out;
  float* acc = (float*)d_ws;                   // [0]=inst, [1]=temp
  float2* ent = (float2*)((char*)d_ws + 256);  // 180208 used, pad to 180224
  unsigned short* pyr = (unsigned short*)((char*)d_ws + 256 + (size_t)180224 * 8);

  constexpr size_t ZOFF[NDEPTH] = {0,        10485760, 15728640, 18350080,
                                   19660800, 20316160, 20643840, 20807680,
                                   20889600, 20930560, 20951040, 20961280};
  constexpr int Ls[NDEPTH] = {2048, 1024, 512, 256, 128, 64, 32, 16, 8, 4, 2, 1};

  zero_kernel<<<1, 64, 0, stream>>>(acc);

  transpose_kernel<<<dim3(T_DIM / 32, C_DIM / 32, 16), dim3(32, 8), 0, stream>>>(z1, z2, pyr);

  // 2-level pools: d0->(d1,d2), ..., d8->(d9,d10), then d10->d11
  for (int d = 0; d <= 8; d += 2) {
    int L2 = Ls[d + 2];
    int n8 = 16 * L2 * C_DIM / 8;
    pool2_kernel<<<dim3((n8 + 255) / 256), 256, 0, stream>>>(
        pyr + ZOFF[d], pyr + ZOFF[d + 1], pyr + ZOFF[d + 2], L2, n8);
  }
  {
    int n8 = 16 * 1 * C_DIM / 8;
    pool_kernel<<<dim3((n8 + 255) / 256), 256, 0, stream>>>(pyr + ZOFF[10],
                                                            pyr + ZOFF[11], 1, n8);
  }

  temp_kernel<<<dim3(1448), 128, 0, stream>>>(pyr, ent, acc);
  inst_kernel<<<dim3(256), 256, 0, stream>>>(pyr, acc);
  merge_kernel<<<dim3(256), 256, 0, stream>>>(ent, acc);

  finalize_kernel<<<1, 64, 0, stream>>>(acc, out);
}

// Round 7
// 378.334 us; speedup vs baseline: 1.3492x; 1.3492x over previous
//
#include <hip/hip_runtime.h>

// TS2Vec hierarchical contrastive loss — bf16 MFMA, per-row online flash-LSE.
//
// Pyramid [16][L][C] bf16 per depth (raw values; Gram scales by the SQUARE of
// any operand pre-scale, so no log2e folding).
//
// temp: row loss = LSE_{c!=r}(S[r,c]) - S[r,partner], S = Z Z^T, M=2L rows.
// One fused launch, 1448 blocks (depth0 col-split x4, depth1 x2).
// Block = 4 waves x 32 rows (128 rows). R6 post-mortem: 64 rows/wave needed
// ~290 regs -> spilled 290MB to scratch under (128,2). 32 rows/wave needs
// ~150 regs -> fits __launch_bounds__(256,3) (cap ~170) WITHOUT spills:
// 12 waves/CU, 3 blocks/CU (LDS 40960B x 3 = 120KB). afrag[2][10] = 80 regs
// holds this wave's 32 rows x whole K; 32-col B tiles staged global->LDS via
// global_load_lds into fragment-ordered 1KB blobs (conflict-free ds_read_b128,
// 5 blobs per wave), double-buffered, ONE barrier per tile.
// Epilogue: per-row online max+sum in raw domain (no cross-lane ops in-loop),
// masks (finite -3e38 sentinel => no NaN) only on wave-uniform slow tiles
// (diag/partner/partial/d>=6). (m,st) partials to ws; merge kernel folds
// chunks; positives linear -> per-wave atomic.
//
// inst: 16x16 Gram via 10 MFMA (A-frag==B-frag since S=ZZ^T), full max pass.
// exp/log base-2 via __builtin_amdgcn_{exp2f,logf}. NOTE: never __exp2f/
// __log2f (glibc math.h reserved-name collision under hipcc g++ driver).

#define B_DIM 8
#define C_DIM 320
#define T_DIM 2048
#define NDEPTH 12
#define LOG2E 1.44269504088896340736f
#define LN2 0.69314718055994530942f
#define FNEG (-3.0e38f)

typedef __attribute__((ext_vector_type(8))) short bf16x8;
typedef __attribute__((ext_vector_type(4))) float f32x4;

#define AS1 __attribute__((address_space(1)))
#define AS3 __attribute__((address_space(3)))

__device__ inline void gload_lds16(const void* g, void* l) {
  __builtin_amdgcn_global_load_lds((const AS1 unsigned int*)g, (AS3 unsigned int*)l,
                                   16, 0, 0);
}

__device__ inline float fast_exp2(float x) { return __builtin_amdgcn_exp2f(x); }
__device__ inline float fast_log2(float x) { return __builtin_amdgcn_logf(x); }

__device__ inline float bf2f(unsigned short s) {
  unsigned u = ((unsigned)s) << 16;
  return __builtin_bit_cast(float, u);
}
__device__ inline unsigned short f2bf(float f) {
  unsigned u = __builtin_bit_cast(unsigned, f);
  u = (u + 0x7FFFu + ((u >> 16) & 1u)) >> 16;  // round-nearest-even
  return (unsigned short)u;
}

// ---------------- tiny utility kernels ----------------
__global__ void zero_kernel(float* acc) {
  if (threadIdx.x < 2) acc[threadIdx.x] = 0.0f;
}

__global__ void finalize_kernel(const float* __restrict__ acc, float* __restrict__ out) {
  if (threadIdx.x == 0) {
    float inst = acc[0] * (1.0f / 11.0f);
    float temp = acc[1] * (1.0f / 11.0f);
    out[0] = 0.5f * inst + 0.5f * temp;  // ALPHA = 0.5
    out[1] = inst;
    out[2] = temp;
  }
}

// ------- transpose+convert: [B][C][T]f32 -> [16][T][C]bf16 (raw) ----------
__global__ __launch_bounds__(256) void transpose_kernel(const float* __restrict__ z1,
                                                        const float* __restrict__ z2,
                                                        unsigned short* __restrict__ out) {
  __shared__ float tile[32][33];
  const int zi = blockIdx.z >> 3;
  const int b = blockIdx.z & 7;
  const float* in = zi ? z2 : z1;
  const int t0 = blockIdx.x * 32;
  const int c0 = blockIdx.y * 32;
  const int tx = threadIdx.x;
  const int ty = threadIdx.y;
#pragma unroll
  for (int k = 0; k < 4; ++k) {
    int c = c0 + ty + k * 8;
    tile[ty + k * 8][tx] = in[((size_t)b * C_DIM + c) * T_DIM + t0 + tx];
  }
  __syncthreads();
#pragma unroll
  for (int k = 0; k < 4; ++k) {
    int t = t0 + ty + k * 8;
    out[((size_t)(zi * B_DIM + b) * T_DIM + t) * C_DIM + c0 + tx] = f2bf(tile[tx][ty + k * 8]);
  }
}

// ---------------- max-pool: one level ------------------------------------
__global__ __launch_bounds__(256) void pool_kernel(const unsigned short* __restrict__ in,
                                                   unsigned short* __restrict__ out,
                                                   int Lout, int n8) {
  int idx = blockIdx.x * 256 + threadIdx.x;
  if (idx >= n8) return;
  int e = idx * 8;
  int c = e % C_DIM;
  int row = e / C_DIM;
  int bb = row / Lout;
  int l = row % Lout;
  size_t base = ((size_t)(bb * 2 * Lout + 2 * l)) * C_DIM + c;
  bf16x8 a = *(const bf16x8*)(in + base);
  bf16x8 b = *(const bf16x8*)(in + base + C_DIM);
  bf16x8 o;
#pragma unroll
  for (int k = 0; k < 8; ++k) {
    unsigned short ua = (unsigned short)a[k], ub = (unsigned short)b[k];
    o[k] = (short)(bf2f(ua) > bf2f(ub) ? ua : ub);
  }
  *(bf16x8*)(out + (size_t)e) = o;
}

// ---------------- max-pool: two levels in one pass -----------------------
__global__ __launch_bounds__(256) void pool2_kernel(const unsigned short* __restrict__ in,
                                                    unsigned short* __restrict__ out1,
                                                    unsigned short* __restrict__ out2,
                                                    int L2out, int n8) {
  int idx = blockIdx.x * 256 + threadIdx.x;
  if (idx >= n8) return;
  int e = idx * 8;
  int c = e % C_DIM;
  int row = e / C_DIM;
  int bb = row / L2out;
  int l = row % L2out;
  size_t base = ((size_t)(bb * 4 * L2out + 4 * l)) * C_DIM + c;
  bf16x8 a = *(const bf16x8*)(in + base);
  bf16x8 b = *(const bf16x8*)(in + base + C_DIM);
  bf16x8 cc = *(const bf16x8*)(in + base + 2 * C_DIM);
  bf16x8 dd = *(const bf16x8*)(in + base + 3 * C_DIM);
  bf16x8 m01, m23, m03;
#pragma unroll
  for (int k = 0; k < 8; ++k) {
    unsigned short ua = (unsigned short)a[k], ub = (unsigned short)b[k];
    unsigned short uc = (unsigned short)cc[k], ud = (unsigned short)dd[k];
    unsigned short x = bf2f(ua) > bf2f(ub) ? ua : ub;
    unsigned short y = bf2f(uc) > bf2f(ud) ? uc : ud;
    m01[k] = (short)x;
    m23[k] = (short)y;
    m03[k] = (short)(bf2f(x) > bf2f(y) ? x : y);
  }
  size_t o1 = ((size_t)(bb * 2 * L2out + 2 * l)) * C_DIM + c;
  *(bf16x8*)(out1 + o1) = m01;
  *(bf16x8*)(out1 + o1 + C_DIM) = m23;
  *(bf16x8*)(out2 + (size_t)e) = m03;
}

// ---------------- fused temp loss ----------------------------------------
__global__ __launch_bounds__(256, 3) void temp_kernel(const unsigned short* __restrict__ pyr,
                                                      float2* __restrict__ ent,
                                                      float* __restrict__ acc) {
  constexpr int Ls[NDEPTH] = {2048, 1024, 512, 256, 128, 64, 32, 16, 8, 4, 2, 1};
  constexpr int SP[NDEPTH] = {4, 2, 1, 1, 1, 1, 1, 1, 1, 1, 1, 1};
  constexpr int NB[NDEPTH] = {1024, 256, 64, 32, 16, 8, 8, 8, 8, 8, 8, 8};
  constexpr size_t ZOFF[NDEPTH] = {0,        10485760, 15728640, 18350080,
                                   19660800, 20316160, 20643840, 20807680,
                                   20889600, 20930560, 20951040, 20961280};
  constexpr size_t EBASE[NDEPTH] = {0,      131072, 163840, 172032, 176128, 178176,
                                    179200, 179712, 179968, 180096, 180160, 180192};
  constexpr float SCL[NDEPTH] = {
      1.f / (16 * 2048.f), 1.f / (16 * 1024.f), 1.f / (16 * 512.f), 1.f / (16 * 256.f),
      1.f / (16 * 128.f),  1.f / (16 * 64.f),   1.f / (16 * 32.f),  1.f / (16 * 16.f),
      1.f / (16 * 8.f),    1.f / (16 * 4.f),    1.f / (16 * 2.f),   1.f / (16 * 1.f)};

  __shared__ __align__(16) unsigned short Bs[2 * 10240];  // exactly 40960 B

  int bid = blockIdx.x;
  int d = 0;
  while (bid >= NB[d]) { bid -= NB[d]; ++d; }
  const int L = Ls[d], M = 2 * L, sp = SP[d];
  const int csz = M / sp;
  const int ntiles = (csz + 31) >> 5;
  const int b = bid & 7;  // batch fastest -> XCD L2 affinity
  const int t2 = bid >> 3;
  const int chunk = t2 % sp;
  const int rb = t2 / sp;
  const int r0 = rb * 128;
  const int cbase = chunk * csz;
  const float scale = SCL[d];
  const unsigned short* Z = pyr + ZOFF[d];

  const int tid = threadIdx.x;
  const int w = tid >> 6, lane = tid & 63;
  const int lr = lane & 15, lg = lane >> 4;

  auto rowptr = [&](int r) -> const unsigned short* {
    r = (r < M) ? r : (M - 1);
    int idx = (r < L) ? (b * L + r) : ((B_DIM + b) * L + (r - L));
    return Z + (size_t)idx * C_DIM;
  };

  // stage column tile ct: 20 blobs split 5 per wave
  auto stage = [&](int buf, int ct) {
    const int c0 = cbase + ct * 32;
#pragma unroll
    for (int i = 0; i < 5; ++i) {
      int blob = w * 5 + i;           // 0..19
      int ks = blob >> 1, sub = blob & 1;
      const unsigned short* g = rowptr(c0 + sub * 16 + lr) + ks * 32 + lg * 8;
      gload_lds16(g, &Bs[buf * 10240 + blob * 512]);
    }
  };

  // A fragments: this wave's 32 rows, whole K (80 regs)
  const int rwave = r0 + w * 32;
  bf16x8 afrag[2][10];
#pragma unroll
  for (int rs = 0; rs < 2; ++rs) {
    const unsigned short* rp = rowptr(rwave + rs * 16 + lr) + lg * 8;
#pragma unroll
    for (int ks = 0; ks < 10; ++ks) afrag[rs][ks] = *(const bf16x8*)(rp + ks * 32);
  }

  // wave-uniform slow-tile ranges (32 rows per wave, all in one half for d<=5)
  const int rlo = rwave, rhi = rwave + 31;
  int plo = 1, phi = 0;  // empty
  if (d <= 5) {          // L>=64, rwave%32==0 -> rows lie in one half
    plo = (rlo < L) ? rlo + L : rlo - L;
    phi = plo + 31;
  }

  // per-lane per-row online state (raw domain): 8 rows (2 rs x 4 rg)
  float m_[8], s_[8];
  float pacc = 0.f;
#pragma unroll
  for (int i = 0; i < 8; ++i) { m_[i] = FNEG; s_[i] = 0.f; }

  stage(0, 0);
  __syncthreads();

  for (int ct = 0; ct < ntiles; ++ct) {
    const int cur = ct & 1;
    if (ct + 1 < ntiles) stage(1 - cur, ct + 1);

    f32x4 c4[2][2];
#pragma unroll
    for (int rs = 0; rs < 2; ++rs)
#pragma unroll
      for (int cs = 0; cs < 2; ++cs) c4[rs][cs] = (f32x4){0.f, 0.f, 0.f, 0.f};

#pragma unroll
    for (int ks = 0; ks < 10; ++ks) {
      bf16x8 b0 = *(const bf16x8*)&Bs[cur * 10240 + (ks * 2 + 0) * 512 + lane * 8];
      bf16x8 b1 = *(const bf16x8*)&Bs[cur * 10240 + (ks * 2 + 1) * 512 + lane * 8];
#pragma unroll
      for (int rs = 0; rs < 2; ++rs) {
        c4[rs][0] = __builtin_amdgcn_mfma_f32_16x16x32_bf16(afrag[rs][ks], b0, c4[rs][0], 0, 0, 0);
        c4[rs][1] = __builtin_amdgcn_mfma_f32_16x16x32_bf16(afrag[rs][ks], b1, c4[rs][1], 0, 0, 0);
      }
    }

    const int gclo = cbase + ct * 32, gchi = gclo + 31;
    bool slow = (d >= 6) ||
                (gchi >= rlo && gclo <= rhi) ||   // diagonal in tile
                (gchi >= plo && gclo <= phi);     // partner col in tile

    if (slow) {
      const int gc0 = gclo + lr, gc1 = gc0 + 16;
#pragma unroll
      for (int rs = 0; rs < 2; ++rs) {
#pragma unroll
        for (int rg = 0; rg < 4; ++rg) {
          int gr = rwave + rs * 16 + lg * 4 + rg;
          int prt = (gr < L) ? (gr + L) : (gr - L);
          float v0 = c4[rs][0][rg], v1 = c4[rs][1][rg];
          if (gr < M) {
            if (gc0 == prt) pacc += v0;
            if (gc1 == prt) pacc += v1;
          }
          float x0 = (gc0 < M && gc0 != gr) ? v0 : FNEG;
          float x1 = (gc1 < M && gc1 != gr) ? v1 : FNEG;
          int i = rs * 4 + rg;
          float mn = fmaxf(m_[i], fmaxf(x0, x1));
          float f = (m_[i] - mn) * LOG2E;   // may hit -inf: exp2->0, no NaN
          s_[i] = s_[i] * fast_exp2(f) + fast_exp2((x0 - mn) * LOG2E) +
                  fast_exp2((x1 - mn) * LOG2E);
          m_[i] = mn;
        }
      }
    } else {  // fast path: no masks, no compares
#pragma unroll
      for (int rs = 0; rs < 2; ++rs) {
#pragma unroll
        for (int rg = 0; rg < 4; ++rg) {
          float v0 = c4[rs][0][rg], v1 = c4[rs][1][rg];
          int i = rs * 4 + rg;
          float mn = fmaxf(m_[i], fmaxf(v0, v1));
          float f = (m_[i] - mn) * LOG2E;
          s_[i] = s_[i] * fast_exp2(f) + fast_exp2((v0 - mn) * LOG2E) +
                  fast_exp2((v1 - mn) * LOG2E);
          m_[i] = mn;
        }
      }
    }
    __syncthreads();  // buf[cur] reads done AND staged loads drained
  }

  // merge (m,s) across the 16 lr-lanes of each row, write per-row-chunk partial
#pragma unroll
  for (int rs = 0; rs < 2; ++rs) {
#pragma unroll
    for (int rg = 0; rg < 4; ++rg) {
      int i = rs * 4 + rg;
      float m = m_[i], s = s_[i];
      float mt = m;
#pragma unroll
      for (int k = 1; k < 16; k <<= 1) mt = fmaxf(mt, __shfl_xor(mt, k));
      float st = s * fast_exp2((m - mt) * LOG2E);
#pragma unroll
      for (int k = 1; k < 16; k <<= 1) st += __shfl_xor(st, k);
      int gr = rwave + rs * 16 + lg * 4 + rg;
      if (gr < M && lr == 0)
        ent[EBASE[d] + ((size_t)(b * M + gr)) * sp + chunk] = make_float2(mt, st);
    }
  }

  // positives: raw domain, one atomic per wave
#pragma unroll
  for (int k = 1; k < 64; k <<= 1) pacc += __shfl_xor(pacc, k);
  if (lane == 0) atomicAdd(acc + 1, -pacc * scale);
}

// ---------------- merge column-chunk partials -> temp loss ----------------
__global__ __launch_bounds__(256) void merge_kernel(const float2* __restrict__ ent,
                                                    float* __restrict__ acc) {
  constexpr int Ls[NDEPTH] = {2048, 1024, 512, 256, 128, 64, 32, 16, 8, 4, 2, 1};
  constexpr int SP[NDEPTH] = {4, 2, 1, 1, 1, 1, 1, 1, 1, 1, 1, 1};
  constexpr size_t EBASE[NDEPTH] = {0,      131072, 163840, 172032, 176128, 178176,
                                    179200, 179712, 179968, 180096, 180160, 180192};
  constexpr int RBASE[NDEPTH] = {0,     32768, 49152, 57344, 61440, 63488,
                                 64512, 65024, 65280, 65408, 65472, 65504};
  __shared__ float red[4];
  int i = blockIdx.x * 256 + threadIdx.x;
  float partial = 0.f;
  if (i < 65520) {
    int d = 0;
    while (d < 11 && i >= RBASE[d + 1]) ++d;
    int rem = i - RBASE[d];
    int sp = SP[d];
    const float2* e = ent + EBASE[d] + (size_t)rem * sp;
    float mt = FNEG;
    for (int c = 0; c < sp; ++c) mt = fmaxf(mt, e[c].x);
    float st = 0.f;
    for (int c = 0; c < sp; ++c) st += e[c].y * fast_exp2((e[c].x - mt) * LOG2E);
    // natural-log LSE = mt + ln2 * log2(st)
    partial = (mt + LN2 * fast_log2(st)) / (16.f * (float)Ls[d]);
  }
#pragma unroll
  for (int k = 1; k < 64; k <<= 1) partial += __shfl_xor(partial, k);
  if ((threadIdx.x & 63) == 0) red[threadIdx.x >> 6] = partial;
  __syncthreads();
  if (threadIdx.x == 0) atomicAdd(acc + 1, red[0] + red[1] + red[2] + red[3]);
}

// ---------------- fused inst loss: 16x16 Gram via MFMA --------------------
__global__ __launch_bounds__(256) void inst_kernel(const unsigned short* __restrict__ pyr,
                                                   float* __restrict__ acc) {
  constexpr int Ls[NDEPTH] = {2048, 1024, 512, 256, 128, 64, 32, 16, 8, 4, 2, 1};
  constexpr size_t ZOFF[NDEPTH] = {0,        10485760, 15728640, 18350080,
                                   19660800, 20316160, 20643840, 20807680,
                                   20889600, 20930560, 20951040, 20961280};
  constexpr float SCL[NDEPTH] = {
      1.f / (16 * 2048.f), 1.f / (16 * 1024.f), 1.f / (16 * 512.f), 1.f / (16 * 256.f),
      1.f / (16 * 128.f),  1.f / (16 * 64.f),   1.f / (16 * 32.f),  1.f / (16 * 16.f),
      1.f / (16 * 8.f),    1.f / (16 * 4.f),    1.f / (16 * 2.f),   1.f / (16 * 1.f)};
  __shared__ float red[4];
  const int tid = threadIdx.x;
  const int w = tid >> 6, lane = tid & 63, lr = lane & 15, lg = lane >> 4;
  const int gw = blockIdx.x * 4 + w;
  const int nw = gridDim.x * 4;
  float partial = 0.f;

  for (int gl = gw; gl < 4095; gl += nw) {
    int d = 0, l = gl;
    while (l >= Ls[d]) { l -= Ls[d]; ++d; }
    const int L = Ls[d];
    const unsigned short* Z = pyr + ZOFF[d];

    const unsigned short* rp = Z + ((size_t)lr * L + l) * C_DIM + lg * 8;
    bf16x8 fr[10];
#pragma unroll
    for (int ks = 0; ks < 10; ++ks) fr[ks] = *(const bf16x8*)(rp + ks * 32);
    f32x4 c4 = (f32x4){0.f, 0.f, 0.f, 0.f};
#pragma unroll
    for (int ks = 0; ks < 10; ++ks)
      c4 = __builtin_amdgcn_mfma_f32_16x16x32_bf16(fr[ks], fr[ks], c4, 0, 0, 0);

#pragma unroll
    for (int rg = 0; rg < 4; ++rg) {
      int gr = lg * 4 + rg, gc = lr;
      float v = c4[rg];
      int prt = (gr + 8) & 15;
      float ps = (gc == prt) ? v : 0.f;
      float x = (gc != gr) ? v * LOG2E : FNEG;
      float mx = x;
#pragma unroll
      for (int k = 1; k < 16; k <<= 1) mx = fmaxf(mx, __shfl_xor(mx, k));
      float se = fast_exp2(fmaxf(x - mx, -128.f));
#pragma unroll
      for (int k = 1; k < 16; k <<= 1) {
        se += __shfl_xor(se, k);
        ps += __shfl_xor(ps, k);
      }
      if (lr == 0) partial += ((mx + fast_log2(se)) * LN2 - ps) * SCL[d];
    }
  }

#pragma unroll
  for (int k = 1; k < 64; k <<= 1) partial += __shfl_xor(partial, k);
  if ((tid & 63) == 0) red[tid >> 6] = partial;
  __syncthreads();
  if (tid == 0) atomicAdd(acc, red[0] + red[1] + red[2] + red[3]);
}

// ---------------- launch ----------------
extern "C" void kernel_launch(void* const* d_in, const int* in_sizes, int n_in,
                              void* d_out, int out_size, void* d_ws, size_t ws_size,
                              hipStream_t stream) {
  const float* z1 = (const float*)d_in[0];
  const float* z2 = (const float*)d_in[1];
  float* out = (float*)d_out;
  float* acc = (float*)d_ws;                   // [0]=inst, [1]=temp
  float2* ent = (float2*)((char*)d_ws + 256);  // 180208 used, pad to 180224
  unsigned short* pyr = (unsigned short*)((char*)d_ws + 256 + (size_t)180224 * 8);

  constexpr size_t ZOFF[NDEPTH] = {0,        10485760, 15728640, 18350080,
                                   19660800, 20316160, 20643840, 20807680,
                                   20889600, 20930560, 20951040, 20961280};
  constexpr int Ls[NDEPTH] = {2048, 1024, 512, 256, 128, 64, 32, 16, 8, 4, 2, 1};

  zero_kernel<<<1, 64, 0, stream>>>(acc);

  transpose_kernel<<<dim3(T_DIM / 32, C_DIM / 32, 16), dim3(32, 8), 0, stream>>>(z1, z2, pyr);

  // 2-level pools: d0->(d1,d2), ..., d8->(d9,d10), then d10->d11
  for (int d = 0; d <= 8; d += 2) {
    int L2 = Ls[d + 2];
    int n8 = 16 * L2 * C_DIM / 8;
    pool2_kernel<<<dim3((n8 + 255) / 256), 256, 0, stream>>>(
        pyr + ZOFF[d], pyr + ZOFF[d + 1], pyr + ZOFF[d + 2], L2, n8);
  }
  {
    int n8 = 16 * 1 * C_DIM / 8;
    pool_kernel<<<dim3((n8 + 255) / 256), 256, 0, stream>>>(pyr + ZOFF[10],
                                                            pyr + ZOFF[11], 1, n8);
  }

  temp_kernel<<<dim3(1448), 256, 0, stream>>>(pyr, ent, acc);
  inst_kernel<<<dim3(256), 256, 0, stream>>>(pyr, acc);
  merge_kernel<<<dim3(256), 256, 0, stream>>>(ent, acc);

  finalize_kernel<<<1, 64, 0, stream>>>(acc, out);
}

// Round 8
// 290.891 us; speedup vs baseline: 1.7548x; 1.3006x over previous
//
#include <hip/hip_runtime.h>

// TS2Vec hierarchical contrastive loss — bf16 MFMA, pipelined fixed-bias LSE.
//
// Pyramid [16][L][C] bf16 per depth (raw values; Gram scales by the SQUARE of
// any operand pre-scale, so no log2e folding).
//
// temp: row loss = LSE_{c!=r}(S[r,c]) - S[r,partner], S = Z Z^T, M=2L rows.
// Fused launch: blocks [0,1448) temp (depth0 col-split x4, depth1 x2),
// blocks [1448,1704) inst. Block = 4 waves x 32 rows; A (whole K=320) in 80
// regs/wave; 32-col B tiles staged via global_load_lds (fragment-ordered 1KB
// blobs, conflict-free ds_read_b128), double-buffered.
//
// R7 post-mortem: 2-3 waves/SIMD (afrag cost) + ~1000cyc serial chain per
// tile (ds->MFMA->epilogue->barrier) = waves stalled 90%. R8 = ILP instead of
// TLP: software pipeline — iteration ct runs MFMA(ct) into one accumulator
// set and epilogue(ct-1) on the other (cA/cB, no runtime indexing -> no
// scratch), so MFMA + VALU pipes overlap within each wave. Epilogue diet:
// fixed per-lane-row bias (init at always-slow tile 0), fast tile =
// fma + exp2 + add per entry; __any(f>60) rescue re-raises bias (exact:
// merge kernel rescales (m,s); lanes stuck at bias=FNEG are annihilated by
// exp2(FNEG-mt)=0 in the merge). Staging pointers hoisted: advance 32 cols
// per tile, one-time +7*L*C jump at the z1->z2 half boundary.
//
// exp/log base-2 via __builtin_amdgcn_{exp2f,logf}. NOTE: never __exp2f/
// __log2f (glibc math.h reserved-name collision under hipcc g++ driver).

#define B_DIM 8
#define C_DIM 320
#define T_DIM 2048
#define NDEPTH 12
#define LOG2E 1.44269504088896340736f
#define LN2 0.69314718055994530942f
#define FNEG (-3.0e38f)
#define NBLK_TEMP 1448
#define NBLK_INST 256

typedef __attribute__((ext_vector_type(8))) short bf16x8;
typedef __attribute__((ext_vector_type(4))) float f32x4;

#define AS1 __attribute__((address_space(1)))
#define AS3 __attribute__((address_space(3)))

__device__ inline void gload_lds16(const void* g, void* l) {
  __builtin_amdgcn_global_load_lds((const AS1 unsigned int*)g, (AS3 unsigned int*)l,
                                   16, 0, 0);
}

__device__ inline float fast_exp2(float x) { return __builtin_amdgcn_exp2f(x); }
__device__ inline float fast_log2(float x) { return __builtin_amdgcn_logf(x); }

__device__ inline float bf2f(unsigned short s) {
  unsigned u = ((unsigned)s) << 16;
  return __builtin_bit_cast(float, u);
}
__device__ inline unsigned short f2bf(float f) {
  unsigned u = __builtin_bit_cast(unsigned, f);
  u = (u + 0x7FFFu + ((u >> 16) & 1u)) >> 16;  // round-nearest-even
  return (unsigned short)u;
}

// ---------------- tiny utility kernels ----------------
__global__ void zero_kernel(float* acc) {
  if (threadIdx.x < 2) acc[threadIdx.x] = 0.0f;
}

__global__ void finalize_kernel(const float* __restrict__ acc, float* __restrict__ out) {
  if (threadIdx.x == 0) {
    float inst = acc[0] * (1.0f / 11.0f);
    float temp = acc[1] * (1.0f / 11.0f);
    out[0] = 0.5f * inst + 0.5f * temp;  // ALPHA = 0.5
    out[1] = inst;
    out[2] = temp;
  }
}

// ------- transpose+convert: [B][C][T]f32 -> [16][T][C]bf16 (raw) ----------
__global__ __launch_bounds__(256) void transpose_kernel(const float* __restrict__ z1,
                                                        const float* __restrict__ z2,
                                                        unsigned short* __restrict__ out) {
  __shared__ float tile[32][33];
  const int zi = blockIdx.z >> 3;
  const int b = blockIdx.z & 7;
  const float* in = zi ? z2 : z1;
  const int t0 = blockIdx.x * 32;
  const int c0 = blockIdx.y * 32;
  const int tx = threadIdx.x;
  const int ty = threadIdx.y;
#pragma unroll
  for (int k = 0; k < 4; ++k) {
    int c = c0 + ty + k * 8;
    tile[ty + k * 8][tx] = in[((size_t)b * C_DIM + c) * T_DIM + t0 + tx];
  }
  __syncthreads();
#pragma unroll
  for (int k = 0; k < 4; ++k) {
    int t = t0 + ty + k * 8;
    out[((size_t)(zi * B_DIM + b) * T_DIM + t) * C_DIM + c0 + tx] = f2bf(tile[tx][ty + k * 8]);
  }
}

// ---------------- max-pool: one level ------------------------------------
__global__ __launch_bounds__(256) void pool_kernel(const unsigned short* __restrict__ in,
                                                   unsigned short* __restrict__ out,
                                                   int Lout, int n8) {
  int idx = blockIdx.x * 256 + threadIdx.x;
  if (idx >= n8) return;
  int e = idx * 8;
  int c = e % C_DIM;
  int row = e / C_DIM;
  int bb = row / Lout;
  int l = row % Lout;
  size_t base = ((size_t)(bb * 2 * Lout + 2 * l)) * C_DIM + c;
  bf16x8 a = *(const bf16x8*)(in + base);
  bf16x8 b = *(const bf16x8*)(in + base + C_DIM);
  bf16x8 o;
#pragma unroll
  for (int k = 0; k < 8; ++k) {
    unsigned short ua = (unsigned short)a[k], ub = (unsigned short)b[k];
    o[k] = (short)(bf2f(ua) > bf2f(ub) ? ua : ub);
  }
  *(bf16x8*)(out + (size_t)e) = o;
}

// ---------------- max-pool: two levels in one pass -----------------------
__global__ __launch_bounds__(256) void pool2_kernel(const unsigned short* __restrict__ in,
                                                    unsigned short* __restrict__ out1,
                                                    unsigned short* __restrict__ out2,
                                                    int L2out, int n8) {
  int idx = blockIdx.x * 256 + threadIdx.x;
  if (idx >= n8) return;
  int e = idx * 8;
  int c = e % C_DIM;
  int row = e / C_DIM;
  int bb = row / L2out;
  int l = row % L2out;
  size_t base = ((size_t)(bb * 4 * L2out + 4 * l)) * C_DIM + c;
  bf16x8 a = *(const bf16x8*)(in + base);
  bf16x8 b = *(const bf16x8*)(in + base + C_DIM);
  bf16x8 cc = *(const bf16x8*)(in + base + 2 * C_DIM);
  bf16x8 dd = *(const bf16x8*)(in + base + 3 * C_DIM);
  bf16x8 m01, m23, m03;
#pragma unroll
  for (int k = 0; k < 8; ++k) {
    unsigned short ua = (unsigned short)a[k], ub = (unsigned short)b[k];
    unsigned short uc = (unsigned short)cc[k], ud = (unsigned short)dd[k];
    unsigned short x = bf2f(ua) > bf2f(ub) ? ua : ub;
    unsigned short y = bf2f(uc) > bf2f(ud) ? uc : ud;
    m01[k] = (short)x;
    m23[k] = (short)y;
    m03[k] = (short)(bf2f(x) > bf2f(y) ? x : y);
  }
  size_t o1 = ((size_t)(bb * 2 * L2out + 2 * l)) * C_DIM + c;
  *(bf16x8*)(out1 + o1) = m01;
  *(bf16x8*)(out1 + o1 + C_DIM) = m23;
  *(bf16x8*)(out2 + (size_t)e) = m03;
}

// ---------------- fused temp + inst loss ----------------------------------
__global__ __launch_bounds__(256, 2) void temp_kernel(const unsigned short* __restrict__ pyr,
                                                      float2* __restrict__ ent,
                                                      float* __restrict__ acc) {
  constexpr int Ls[NDEPTH] = {2048, 1024, 512, 256, 128, 64, 32, 16, 8, 4, 2, 1};
  constexpr int SP[NDEPTH] = {4, 2, 1, 1, 1, 1, 1, 1, 1, 1, 1, 1};
  constexpr int NB[NDEPTH] = {1024, 256, 64, 32, 16, 8, 8, 8, 8, 8, 8, 8};
  constexpr size_t ZOFF[NDEPTH] = {0,        10485760, 15728640, 18350080,
                                   19660800, 20316160, 20643840, 20807680,
                                   20889600, 20930560, 20951040, 20961280};
  constexpr size_t EBASE[NDEPTH] = {0,      131072, 163840, 172032, 176128, 178176,
                                    179200, 179712, 179968, 180096, 180160, 180192};
  constexpr float SCL[NDEPTH] = {
      1.f / (16 * 2048.f), 1.f / (16 * 1024.f), 1.f / (16 * 512.f), 1.f / (16 * 256.f),
      1.f / (16 * 128.f),  1.f / (16 * 64.f),   1.f / (16 * 32.f),  1.f / (16 * 16.f),
      1.f / (16 * 8.f),    1.f / (16 * 4.f),    1.f / (16 * 2.f),   1.f / (16 * 1.f)};

  __shared__ __align__(16) unsigned short Bs[2 * 10240];  // exactly 40960 B

  const int tid = threadIdx.x;
  const int w = tid >> 6, lane = tid & 63;
  const int lr = lane & 15, lg = lane >> 4;

  // ================= inst path (blocks >= NBLK_TEMP) =================
  if (blockIdx.x >= NBLK_TEMP) {
    const int gw = (blockIdx.x - NBLK_TEMP) * 4 + w;
    const int nw = NBLK_INST * 4;
    float partial = 0.f;
    for (int gl = gw; gl < 4095; gl += nw) {
      int d = 0, l = gl;
      while (l >= Ls[d]) { l -= Ls[d]; ++d; }
      const int L = Ls[d];
      const unsigned short* Z = pyr + ZOFF[d];
      const unsigned short* rp = Z + ((size_t)lr * L + l) * C_DIM + lg * 8;
      bf16x8 fr[10];
#pragma unroll
      for (int ks = 0; ks < 10; ++ks) fr[ks] = *(const bf16x8*)(rp + ks * 32);
      f32x4 c4 = (f32x4){0.f, 0.f, 0.f, 0.f};
#pragma unroll
      for (int ks = 0; ks < 10; ++ks)
        c4 = __builtin_amdgcn_mfma_f32_16x16x32_bf16(fr[ks], fr[ks], c4, 0, 0, 0);
#pragma unroll
      for (int rg = 0; rg < 4; ++rg) {
        int gr = lg * 4 + rg, gc = lr;
        float v = c4[rg];
        int prt = (gr + 8) & 15;
        float ps = (gc == prt) ? v : 0.f;
        float x = (gc != gr) ? v * LOG2E : FNEG;
        float mx = x;
#pragma unroll
        for (int k = 1; k < 16; k <<= 1) mx = fmaxf(mx, __shfl_xor(mx, k));
        float se = fast_exp2(fmaxf(x - mx, -128.f));
#pragma unroll
        for (int k = 1; k < 16; k <<= 1) {
          se += __shfl_xor(se, k);
          ps += __shfl_xor(ps, k);
        }
        if (lr == 0) partial += ((mx + fast_log2(se)) * LN2 - ps) * SCL[d];
      }
    }
#pragma unroll
    for (int k = 1; k < 64; k <<= 1) partial += __shfl_xor(partial, k);
    if (lane == 0) atomicAdd(acc, partial);
    return;
  }

  // ================= temp path =================
  int bid = blockIdx.x;
  int d = 0;
  while (bid >= NB[d]) { bid -= NB[d]; ++d; }
  const int L = Ls[d], M = 2 * L, sp = SP[d];
  const int csz = M / sp;
  const int ntiles = (csz + 31) >> 5;
  const int b = bid & 7;  // batch fastest -> XCD L2 affinity
  const int t2 = bid >> 3;
  const int chunk = t2 % sp;
  const int rb = t2 / sp;
  const int r0 = rb * 128;
  const int cbase = chunk * csz;
  const float scale = SCL[d];
  const unsigned short* Z = pyr + ZOFF[d];

  auto rowptr = [&](int r) -> const unsigned short* {
    r = (r < M) ? r : (M - 1);
    int idx = (r < L) ? (b * L + r) : ((B_DIM + b) * L + (r - L));
    return Z + (size_t)idx * C_DIM;
  };

  // A fragments: this wave's 32 rows, whole K (80 regs) — issue early
  const int rwave = r0 + w * 32;
  bf16x8 afrag[2][10];
#pragma unroll
  for (int rs = 0; rs < 2; ++rs) {
    const unsigned short* rp = rowptr(rwave + rs * 16 + lr) + lg * 8;
#pragma unroll
    for (int ks = 0; ks < 10; ++ks) afrag[rs][ks] = *(const bf16x8*)(rp + ks * 32);
  }

  // staging pointers: per-blob, advance 32 cols/tile, +7*L*C at half boundary
  const long stepEl = 32 * (long)C_DIM;
  const long extraEl = (long)7 * L * C_DIM;
  const unsigned short* gp[5];
#pragma unroll
  for (int i = 0; i < 5; ++i) {
    int blob = w * 5 + i, ks = blob >> 1, sub = blob & 1;
    int c = cbase + sub * 16 + lr;
    c = (c < M) ? c : (M - 1);
    long idx = (long)b * L + c + ((c >= L) ? (long)7 * L : 0);
    gp[i] = Z + idx * C_DIM + ks * 32 + lg * 8;
  }
  int c0next = cbase;

  auto stage = [&](int buf) {
#pragma unroll
    for (int i = 0; i < 5; ++i)
      gload_lds16(gp[i], &Bs[buf * 10240 + (w * 5 + i) * 512]);
    long adv = stepEl;
    c0next += 32;
    if (c0next == L) adv += extraEl;
#pragma unroll
    for (int i = 0; i < 5; ++i) gp[i] += adv;
  };

  auto mfmaTile = [&](int buf, f32x4 (&cc)[2][2]) {
#pragma unroll
    for (int rs = 0; rs < 2; ++rs)
#pragma unroll
      for (int cs = 0; cs < 2; ++cs) cc[rs][cs] = (f32x4){0.f, 0.f, 0.f, 0.f};
#pragma unroll
    for (int ks = 0; ks < 10; ++ks) {
      bf16x8 b0 = *(const bf16x8*)&Bs[buf * 10240 + (ks * 2 + 0) * 512 + lane * 8];
      bf16x8 b1 = *(const bf16x8*)&Bs[buf * 10240 + (ks * 2 + 1) * 512 + lane * 8];
#pragma unroll
      for (int rs = 0; rs < 2; ++rs) {
        cc[rs][0] = __builtin_amdgcn_mfma_f32_16x16x32_bf16(afrag[rs][ks], b0, cc[rs][0], 0, 0, 0);
        cc[rs][1] = __builtin_amdgcn_mfma_f32_16x16x32_bf16(afrag[rs][ks], b1, cc[rs][1], 0, 0, 0);
      }
    }
  };

  // wave-uniform slow-tile ranges
  const int rlo = rwave, rhi = rwave + 31;
  int plo = 1, phi = 0;  // empty
  if (d <= 5) {          // L>=64, rwave%32==0 -> rows lie in one half
    plo = (rlo < L) ? rlo + L : rlo - L;
    phi = plo + 31;
  }

  // per-lane per-row state: fixed bias (raw), bias*log2e, sum
  float bias[8], bl2[8], s_[8];
  float pacc = 0.f;
#pragma unroll
  for (int i = 0; i < 8; ++i) { bias[i] = FNEG; bl2[i] = 0.f; s_[i] = 0.f; }

  auto epiSlow = [&](f32x4 (&cp)[2][2], int eclo) {
    const int gc0 = eclo + lr, gc1 = gc0 + 16;
#pragma unroll
    for (int rs = 0; rs < 2; ++rs) {
#pragma unroll
      for (int rg = 0; rg < 4; ++rg) {
        int i = rs * 4 + rg;
        int gr = rwave + rs * 16 + lg * 4 + rg;
        int prt = (gr < L) ? (gr + L) : (gr - L);
        float v0 = cp[rs][0][rg], v1 = cp[rs][1][rg];
        if (gr < M) {
          if (gc0 == prt) pacc += v0;
          if (gc1 == prt) pacc += v1;
        }
        float x0 = (gc0 < M && gc0 != gr) ? v0 : FNEG;
        float x1 = (gc1 < M && gc1 != gr) ? v1 : FNEG;
        float mn = fmaxf(bias[i], fmaxf(x0, x1));
        s_[i] = s_[i] * fast_exp2((bias[i] - mn) * LOG2E) +
                fast_exp2((x0 - mn) * LOG2E) + fast_exp2((x1 - mn) * LOG2E);
        bias[i] = mn;
      }
    }
#pragma unroll
    for (int i = 0; i < 8; ++i) bl2[i] = bias[i] * LOG2E;
  };

  auto epiFast = [&](f32x4 (&cp)[2][2]) {
    // phase A: f = v*log2e - bias*log2e, stored in-place; tile overflow flag
    float flag = FNEG;
#pragma unroll
    for (int rs = 0; rs < 2; ++rs) {
#pragma unroll
      for (int rg = 0; rg < 4; ++rg) {
        int i = rs * 4 + rg;
        float f0 = __builtin_fmaf(cp[rs][0][rg], LOG2E, -bl2[i]);
        float f1 = __builtin_fmaf(cp[rs][1][rg], LOG2E, -bl2[i]);
        cp[rs][0][rg] = f0;
        cp[rs][1][rg] = f1;
        flag = fmaxf(flag, fmaxf(f0, f1));
      }
    }
    if (__any(flag > 60.f)) {  // rare: raise bias online (fast tiles mask-free)
#pragma unroll
      for (int rs = 0; rs < 2; ++rs) {
#pragma unroll
        for (int rg = 0; rg < 4; ++rg) {
          int i = rs * 4 + rg;
          float v0 = (cp[rs][0][rg] + bl2[i]) * LN2;
          float v1 = (cp[rs][1][rg] + bl2[i]) * LN2;
          float mn = fmaxf(bias[i], fmaxf(v0, v1));
          s_[i] = s_[i] * fast_exp2((bias[i] - mn) * LOG2E) +
                  fast_exp2((v0 - mn) * LOG2E) + fast_exp2((v1 - mn) * LOG2E);
          bias[i] = mn;
        }
      }
#pragma unroll
      for (int i = 0; i < 8; ++i) bl2[i] = bias[i] * LOG2E;
    } else {
#pragma unroll
      for (int rs = 0; rs < 2; ++rs)
#pragma unroll
        for (int rg = 0; rg < 4; ++rg)
          s_[rs * 4 + rg] += fast_exp2(cp[rs][0][rg]) + fast_exp2(cp[rs][1][rg]);
    }
  };

  auto epi = [&](f32x4 (&cp)[2][2], int et) {
    const int eclo = cbase + et * 32, echi = eclo + 31;
    bool slowT = (et == 0) || (d >= 6) ||
                 (echi >= rlo && eclo <= rhi) ||   // diagonal in tile
                 (echi >= plo && eclo <= phi);     // partner col in tile
    if (slowT) epiSlow(cp, eclo); else epiFast(cp);
  };

  // ---- software-pipelined main loop ----
  f32x4 cA[2][2], cB[2][2];
  stage(0);
  __syncthreads();
  if (ntiles > 1) stage(1);
  mfmaTile(0, cA);
  __syncthreads();
  for (int ct = 1; ct < ntiles; ++ct) {
    if (ct & 1) {
      if (ct + 1 < ntiles) stage((ct + 1) & 1);
      mfmaTile(1, cB);
      epi(cA, ct - 1);   // independent of cB -> MFMA/VALU overlap
    } else {
      if (ct + 1 < ntiles) stage((ct + 1) & 1);
      mfmaTile(0, cA);
      epi(cB, ct - 1);
    }
    __syncthreads();
  }
  if ((ntiles - 1) & 1) epi(cB, ntiles - 1); else epi(cA, ntiles - 1);

  // merge (bias,s) across the 16 lr-lanes per row, write per-row-chunk partial
#pragma unroll
  for (int rs = 0; rs < 2; ++rs) {
#pragma unroll
    for (int rg = 0; rg < 4; ++rg) {
      int i = rs * 4 + rg;
      float m = bias[i], s = s_[i];
      float mt = m;
#pragma unroll
      for (int k = 1; k < 16; k <<= 1) mt = fmaxf(mt, __shfl_xor(mt, k));
      float st = s * fast_exp2((m - mt) * LOG2E);  // bias=FNEG lanes -> 0
#pragma unroll
      for (int k = 1; k < 16; k <<= 1) st += __shfl_xor(st, k);
      int gr = rwave + rs * 16 + lg * 4 + rg;
      if (gr < M && lr == 0)
        ent[EBASE[d] + ((size_t)(b * M + gr)) * sp + chunk] = make_float2(mt, st);
    }
  }

  // positives (slow tiles only): one atomic per wave
#pragma unroll
  for (int k = 1; k < 64; k <<= 1) pacc += __shfl_xor(pacc, k);
  if (lane == 0) atomicAdd(acc + 1, -pacc * scale);
}

// ---------------- merge column-chunk partials -> temp loss ----------------
__global__ __launch_bounds__(256) void merge_kernel(const float2* __restrict__ ent,
                                                    float* __restrict__ acc) {
  constexpr int Ls[NDEPTH] = {2048, 1024, 512, 256, 128, 64, 32, 16, 8, 4, 2, 1};
  constexpr int SP[NDEPTH] = {4, 2, 1, 1, 1, 1, 1, 1, 1, 1, 1, 1};
  constexpr size_t EBASE[NDEPTH] = {0,      131072, 163840, 172032, 176128, 178176,
                                    179200, 179712, 179968, 180096, 180160, 180192};
  constexpr int RBASE[NDEPTH] = {0,     32768, 49152, 57344, 61440, 63488,
                                 64512, 65024, 65280, 65408, 65472, 65504};
  __shared__ float red[4];
  int i = blockIdx.x * 256 + threadIdx.x;
  float partial = 0.f;
  if (i < 65520) {
    int d = 0;
    while (d < 11 && i >= RBASE[d + 1]) ++d;
    int rem = i - RBASE[d];
    int sp = SP[d];
    const float2* e = ent + EBASE[d] + (size_t)rem * sp;
    float mt = FNEG;
    for (int c = 0; c < sp; ++c) mt = fmaxf(mt, e[c].x);
    float st = 0.f;
    for (int c = 0; c < sp; ++c) st += e[c].y * fast_exp2((e[c].x - mt) * LOG2E);
    partial = (mt + LN2 * fast_log2(st)) / (16.f * (float)Ls[d]);
  }
#pragma unroll
  for (int k = 1; k < 64; k <<= 1) partial += __shfl_xor(partial, k);
  if ((threadIdx.x & 63) == 0) red[threadIdx.x >> 6] = partial;
  __syncthreads();
  if (threadIdx.x == 0) atomicAdd(acc + 1, red[0] + red[1] + red[2] + red[3]);
}

// ---------------- launch ----------------
extern "C" void kernel_launch(void* const* d_in, const int* in_sizes, int n_in,
                              void* d_out, int out_size, void* d_ws, size_t ws_size,
                              hipStream_t stream) {
  const float* z1 = (const float*)d_in[0];
  const float* z2 = (const float*)d_in[1];
  float* out = (float*)d_out;
  float* acc = (float*)d_ws;                   // [0]=inst, [1]=temp
  float2* ent = (float2*)((char*)d_ws + 256);  // 180208 used, pad to 180224
  unsigned short* pyr = (unsigned short*)((char*)d_ws + 256 + (size_t)180224 * 8);

  constexpr size_t ZOFF[NDEPTH] = {0,        10485760, 15728640, 18350080,
                                   19660800, 20316160, 20643840, 20807680,
                                   20889600, 20930560, 20951040, 20961280};
  constexpr int Ls[NDEPTH] = {2048, 1024, 512, 256, 128, 64, 32, 16, 8, 4, 2, 1};

  zero_kernel<<<1, 64, 0, stream>>>(acc);

  transpose_kernel<<<dim3(T_DIM / 32, C_DIM / 32, 16), dim3(32, 8), 0, stream>>>(z1, z2, pyr);

  // 2-level pools: d0->(d1,d2), ..., d8->(d9,d10), then d10->d11
  for (int d = 0; d <= 8; d += 2) {
    int L2 = Ls[d + 2];
    int n8 = 16 * L2 * C_DIM / 8;
    pool2_kernel<<<dim3((n8 + 255) / 256), 256, 0, stream>>>(
        pyr + ZOFF[d], pyr + ZOFF[d + 1], pyr + ZOFF[d + 2], L2, n8);
  }
  {
    int n8 = 16 * 1 * C_DIM / 8;
    pool_kernel<<<dim3((n8 + 255) / 256), 256, 0, stream>>>(pyr + ZOFF[10],
                                                            pyr + ZOFF[11], 1, n8);
  }

  temp_kernel<<<dim3(NBLK_TEMP + NBLK_INST), 256, 0, stream>>>(pyr, ent, acc);
  merge_kernel<<<dim3(256), 256, 0, stream>>>(ent, acc);

  finalize_kernel<<<1, 64, 0, stream>>>(acc, out);
}